// Round 1
// baseline (1208.338 us; speedup 1.0000x reference)
//
#include <hip/hip_runtime.h>
#include <hip/hip_bf16.h>

// Problem constants (match reference)
#define N_CELLS   1000
#define N_GOI     500
#define N_GTOT    5000
#define N_LAT     10
#define NBINS     128     // K
#define N_KNOTS   129     // K+1
#define LOG_NGT   8.517193191416238f   // log(5000)
#define SPLIT     4       // blocks per gene bucket

// ---------------------------------------------------------------------------
// Kernel 1: per-cell logsumexp over all 5000 genes of (baseline + latent@W^T)
// One block per cell.
// ---------------------------------------------------------------------------
__global__ __launch_bounds__(256) void lse_kernel(
    const float* __restrict__ latent,   // [N_CELLS, N_LAT]
    const float* __restrict__ osw,      // [N_GTOT, N_LAT]
    const float* __restrict__ ob,       // [N_GTOT]
    float* __restrict__ lse)            // [N_CELLS]
{
    const int c = blockIdx.x;
    const int t = threadIdx.x;
    float lat[N_LAT];
#pragma unroll
    for (int l = 0; l < N_LAT; ++l) lat[l] = latent[c * N_LAT + l];

    __shared__ float xsh[N_GTOT];
    float m = -1e30f;
    for (int g = t; g < N_GTOT; g += 256) {
        float v = ob[g];
#pragma unroll
        for (int l = 0; l < N_LAT; ++l) v = fmaf(lat[l], osw[g * N_LAT + l], v);
        xsh[g] = v;
        m = fmaxf(m, v);
    }
#pragma unroll
    for (int off = 32; off; off >>= 1) m = fmaxf(m, __shfl_xor(m, off));
    __shared__ float wm[4];
    if ((t & 63) == 0) wm[t >> 6] = m;
    __syncthreads();
    m = fmaxf(fmaxf(wm[0], wm[1]), fmaxf(wm[2], wm[3]));

    float s = 0.0f;
    for (int g = t; g < N_GTOT; g += 256) s += __expf(xsh[g] - m);
#pragma unroll
    for (int off = 32; off; off >>= 1) s += __shfl_xor(s, off);
    __shared__ float wsum[4];
    if ((t & 63) == 0) wsum[t >> 6] = s;
    __syncthreads();
    if (t == 0) lse[c] = m + __logf(wsum[0] + wsum[1] + wsum[2] + wsum[3]);
}

// ---------------------------------------------------------------------------
// Bucketing: histogram by goi = cxg % 500, exclusive scan, scatter cut ids.
// ---------------------------------------------------------------------------
__global__ __launch_bounds__(256) void hist_kernel(
    const int* __restrict__ cxg, int* __restrict__ counts, int n)
{
    int i = blockIdx.x * 256 + threadIdx.x;
    if (i < n) atomicAdd(&counts[cxg[i] % N_GOI], 1);
}

__global__ __launch_bounds__(512) void scan_kernel(
    const int* __restrict__ counts, int* __restrict__ offs, int* __restrict__ cursor)
{
    __shared__ int buf[512];
    const int t = threadIdx.x;
    const int v = (t < N_GOI) ? counts[t] : 0;
    buf[t] = v;
    __syncthreads();
    for (int d = 1; d < 512; d <<= 1) {
        int add = (t >= d) ? buf[t - d] : 0;
        __syncthreads();
        buf[t] += add;
        __syncthreads();
    }
    if (t < N_GOI) {
        int excl = buf[t] - v;
        offs[t] = excl;
        cursor[t] = excl;
    }
    if (t == N_GOI - 1) offs[N_GOI] = buf[t];
}

__global__ __launch_bounds__(256) void scatter_kernel(
    const int* __restrict__ cxg, int* __restrict__ cursor,
    int* __restrict__ list, int n)
{
    int i = blockIdx.x * 256 + threadIdx.x;
    if (i < n) {
        int pos = atomicAdd(&cursor[cxg[i] % N_GOI], 1);
        list[pos] = i;
    }
}

// ---------------------------------------------------------------------------
// Main kernel: one wave per cut, SPLIT*4 waves cooperate on each gene bucket.
// The gene's slope row (10x129 fp32) is held in VGPRs: k = lane (w0),
// k = 64+lane (w1), k = 128 (w2, replicated). Everything about a single cut
// is wave-uniform; shfl reductions give the trapezoid norm, and u_b / u_{b+1}
// come from uniform-lane shuffles.
// ---------------------------------------------------------------------------
__global__ __launch_bounds__(256) void spline_kernel(
    const float* __restrict__ latent,   // [N_CELLS, N_LAT]
    const float* __restrict__ coords,   // [ncuts]
    const int*   __restrict__ genes_oi, // [N_GOI]
    const int*   __restrict__ cxg,      // cut_local_cellxgene_ix  [ncuts]
    const int*   __restrict__ cxg_tot,  // cut_localcellxgene_ix   [ncuts]
    const int*   __restrict__ glocal,   // cut_local_gene_ix       [ncuts]
    const float* __restrict__ hsw,      // [N_GTOT, N_LAT, N_KNOTS]
    const float* __restrict__ osw,      // [N_GTOT, N_LAT]
    const float* __restrict__ ob,       // [N_GTOT]
    const float* __restrict__ sbase,    // [N_GTOT, N_KNOTS]
    const float* __restrict__ lse,      // [N_CELLS]
    const int*   __restrict__ offs,     // [N_GOI+1]
    const int*   __restrict__ list,     // [ncuts]
    float* __restrict__ out)
{
    const int goi  = blockIdx.x / SPLIT;
    const int sub  = blockIdx.x % SPLIT;
    const int lane = threadIdx.x & 63;
    const int wav  = threadIdx.x >> 6;
    const int g    = genes_oi[goi];

    // Load the gene's slope row into registers.
    float w0[N_LAT], w1[N_LAT], w2[N_LAT];
#pragma unroll
    for (int l = 0; l < N_LAT; ++l) {
        const float* p = hsw + (g * N_LAT + l) * N_KNOTS;
        w0[l] = p[lane];
        w1[l] = p[64 + lane];
        w2[l] = p[128];
    }

    const int begin = offs[goi];
    const int end   = offs[goi + 1];
    double acc = 0.0;   // all lanes accumulate identical values; lane 0's is used

    for (int c = begin + sub * 4 + wav; c < end; c += SPLIT * 4) {
        const int   i     = list[c];
        const int   ix    = cxg[i];              // cell*500 + goi
        const int   cell  = ix / N_GOI;
        const float x     = coords[i];
        const int   ix2   = cxg_tot[i];          // cell2*5000 + g2
        const int   cell2 = ix2 / N_GTOT;
        const int   g2    = ix2 - cell2 * N_GTOT;
        const int   gb    = genes_oi[glocal[i]]; // gene for spline_baseline

        float lat[N_LAT];
#pragma unroll
        for (int l = 0; l < N_LAT; ++l) lat[l] = latent[cell * N_LAT + l];

        const float* bp = sbase + gb * N_KNOTS;
        float h0 = bp[lane];
        float h1 = bp[64 + lane];
        float h2 = bp[128];
#pragma unroll
        for (int l = 0; l < N_LAT; ++l) {
            h0 = fmaf(lat[l], w0[l], h0);
            h1 = fmaf(lat[l], w1[l], h1);
            h2 = fmaf(lat[l], w2[l], h2);
        }
        // pdf is invariant to a constant shift of heights -> skip max-subtract
        float u0 = __expf(h0), u1 = __expf(h1), u2 = __expf(h2);
        float ufirst = __shfl(u0, 0);            // u at k=0
        float s = u0 + u1;                       // covers k=0..127
#pragma unroll
        for (int off = 32; off; off >>= 1) s += __shfl_xor(s, off);
        s += u2;                                 // now sum over k=0..128
        float norm = (s - 0.5f * (ufirst + u2)) * (1.0f / (float)NBINS);

        float xsv = fminf(fmaxf(x, 0.0f), 1.0f - 1e-6f) * (float)NBINS;
        int   b   = (int)xsv;                    // floor, xsv >= 0
        b = b < NBINS - 1 ? b : NBINS - 1;
        float alpha = xsv - (float)b;
        int   kk = b + 1;
        // b is wave-uniform -> uniform-lane shuffles
        float left  = (b < 64) ? __shfl(u0, b) : __shfl(u1, b - 64);
        float right = (kk < 64) ? __shfl(u0, kk)
                                : (kk < 128 ? __shfl(u1, kk - 64) : u2);
        float lh = __logf(fmaf(alpha, right - left, left)) - __logf(norm);

        // overall (log softmax) term
        float logit = ob[g2];
#pragma unroll
        for (int l = 0; l < N_LAT; ++l)
            logit = fmaf(latent[cell2 * N_LAT + l], osw[g2 * N_LAT + l], logit);

        float lik = lh + (logit - lse[cell2]) + LOG_NGT;
        acc += (double)lik;
    }

    __shared__ double part[4];
    if (lane == 0) part[wav] = acc;
    __syncthreads();
    if (threadIdx.x == 0) {
        double tot = part[0] + part[1] + part[2] + part[3];
        atomicAdd(out, (float)(-tot));   // elbo = -sum(likelihood)
    }
}

// ---------------------------------------------------------------------------
extern "C" void kernel_launch(void* const* d_in, const int* in_sizes, int n_in,
                              void* d_out, int out_size, void* d_ws, size_t ws_size,
                              hipStream_t stream)
{
    const float* latent   = (const float*)d_in[0];
    const float* coords   = (const float*)d_in[1];
    const int*   genes_oi = (const int*)  d_in[2];
    const int*   cxg      = (const int*)  d_in[3];
    const int*   cxg_tot  = (const int*)  d_in[4];
    const int*   glocal   = (const int*)  d_in[5];
    const float* hsw      = (const float*)d_in[6];
    const float* osw      = (const float*)d_in[7];
    const float* ob       = (const float*)d_in[8];
    const float* sbase    = (const float*)d_in[9];
    const int ncuts = in_sizes[1];

    char* ws = (char*)d_ws;
    float* lse    = (float*)ws;                 // 1000 floats
    int*   counts = (int*)(ws + 4096);          // 500 ints
    int*   offs   = (int*)(ws + 8192);          // 501 ints
    int*   cursor = (int*)(ws + 12288);         // 500 ints
    int*   list   = (int*)(ws + 16384);         // ncuts ints
    float* out    = (float*)d_out;

    hipMemsetAsync(out, 0, sizeof(float), stream);
    hipMemsetAsync(counts, 0, N_GOI * sizeof(int), stream);

    lse_kernel<<<N_CELLS, 256, 0, stream>>>(latent, osw, ob, lse);
    hist_kernel<<<(ncuts + 255) / 256, 256, 0, stream>>>(cxg, counts, ncuts);
    scan_kernel<<<1, 512, 0, stream>>>(counts, offs, cursor);
    scatter_kernel<<<(ncuts + 255) / 256, 256, 0, stream>>>(cxg, cursor, list, ncuts);
    spline_kernel<<<N_GOI * SPLIT, 256, 0, stream>>>(
        latent, coords, genes_oi, cxg, cxg_tot, glocal,
        hsw, osw, ob, sbase, lse, offs, list, out);
}

// Round 2
// 617.565 us; speedup vs baseline: 1.9566x; 1.9566x over previous
//
#include <hip/hip_runtime.h>
#include <hip/hip_bf16.h>

// Problem constants (match reference)
#define N_CELLS   1000
#define N_GOI     500
#define N_GTOT    5000
#define N_LAT     10
#define NBINS     128     // K
#define N_KNOTS   129     // K+1
#define LOG_NGT   8.517193191416238f   // log(5000)
#define SPLIT     4       // blocks per gene bucket (spline kernel)

// ---------------------------------------------------------------------------
// Kernel 1: per-cell logsumexp over all 5000 genes of (baseline + latent@W^T)
// One block per cell.
// ---------------------------------------------------------------------------
__global__ __launch_bounds__(256) void lse_kernel(
    const float* __restrict__ latent,   // [N_CELLS, N_LAT]
    const float* __restrict__ osw,      // [N_GTOT, N_LAT]
    const float* __restrict__ ob,       // [N_GTOT]
    float* __restrict__ lse)            // [N_CELLS]
{
    const int c = blockIdx.x;
    const int t = threadIdx.x;
    float lat[N_LAT];
#pragma unroll
    for (int l = 0; l < N_LAT; ++l) lat[l] = latent[c * N_LAT + l];

    __shared__ float xsh[N_GTOT];
    float m = -1e30f;
    for (int g = t; g < N_GTOT; g += 256) {
        float v = ob[g];
#pragma unroll
        for (int l = 0; l < N_LAT; ++l) v = fmaf(lat[l], osw[g * N_LAT + l], v);
        xsh[g] = v;
        m = fmaxf(m, v);
    }
#pragma unroll
    for (int off = 32; off; off >>= 1) m = fmaxf(m, __shfl_xor(m, off));
    __shared__ float wm[4];
    if ((t & 63) == 0) wm[t >> 6] = m;
    __syncthreads();
    m = fmaxf(fmaxf(wm[0], wm[1]), fmaxf(wm[2], wm[3]));

    float s = 0.0f;
    for (int g = t; g < N_GTOT; g += 256) s += __expf(xsh[g] - m);
#pragma unroll
    for (int off = 32; off; off >>= 1) s += __shfl_xor(s, off);
    __shared__ float wsum[4];
    if ((t & 63) == 0) wsum[t >> 6] = s;
    __syncthreads();
    if (t == 0) lse[c] = m + __logf(wsum[0] + wsum[1] + wsum[2] + wsum[3]);
}

// ---------------------------------------------------------------------------
// Histogram by goi = cxg % 500 with LDS privatization.
// ---------------------------------------------------------------------------
__global__ __launch_bounds__(256) void hist_kernel(
    const int* __restrict__ cxg, int* __restrict__ counts, int n)
{
    __shared__ int h[N_GOI];
    const int t = threadIdx.x;
    for (int b = t; b < N_GOI; b += 256) h[b] = 0;
    __syncthreads();
    const int stride = gridDim.x * 256;
    for (int i = blockIdx.x * 256 + t; i < n; i += stride)
        atomicAdd(&h[((unsigned)cxg[i]) % N_GOI], 1);
    __syncthreads();
    for (int b = t; b < N_GOI; b += 256) {
        int v = h[b];
        if (v) atomicAdd(&counts[b], v);
    }
}

__global__ __launch_bounds__(512) void scan_kernel(
    const int* __restrict__ counts, int* __restrict__ offs, int* __restrict__ cursor)
{
    __shared__ int buf[512];
    const int t = threadIdx.x;
    const int v = (t < N_GOI) ? counts[t] : 0;
    buf[t] = v;
    __syncthreads();
    for (int d = 1; d < 512; d <<= 1) {
        int add = (t >= d) ? buf[t - d] : 0;
        __syncthreads();
        buf[t] += add;
        __syncthreads();
    }
    if (t < N_GOI) {
        int excl = buf[t] - v;
        offs[t] = excl;
        cursor[t] = excl;
    }
    if (t == N_GOI - 1) offs[N_GOI] = buf[t];
}

// ---------------------------------------------------------------------------
// Fused gather: thread-per-cut.
//  - computes the full overall/log-softmax term and reduces it into out
//  - packs {coord, cell*8192+gb} per cut into its gene bucket (coalesced
//    float2 record for the spline kernel; pos from per-bin cursor atomics)
// ---------------------------------------------------------------------------
__global__ __launch_bounds__(256) void gather_kernel(
    const float* __restrict__ latent,   // [N_CELLS, N_LAT]
    const float* __restrict__ coords,   // [ncuts]
    const int*   __restrict__ genes_oi, // [N_GOI]
    const int*   __restrict__ cxg,      // cut_local_cellxgene_ix  [ncuts]
    const int*   __restrict__ cxg_tot,  // cut_localcellxgene_ix   [ncuts]
    const int*   __restrict__ glocal,   // cut_local_gene_ix       [ncuts]
    const float* __restrict__ osw,      // [N_GTOT, N_LAT]
    const float* __restrict__ ob,       // [N_GTOT]
    const float* __restrict__ lse,      // [N_CELLS]
    int*   __restrict__ cursor,         // [N_GOI]
    float2* __restrict__ xpk,           // [ncuts] packed records
    float* __restrict__ out, int n)
{
    const int t = threadIdx.x;
    const int stride = gridDim.x * 256;
    double ovs = 0.0;
    for (int i = blockIdx.x * 256 + t; i < n; i += stride) {
        const unsigned ix  = (unsigned)cxg[i];
        const unsigned goi = ix % N_GOI;
        const unsigned cell = ix / N_GOI;
        const int gb = genes_oi[glocal[i]];
        const int pos = atomicAdd(&cursor[goi], 1);
        float2 rec;
        rec.x = coords[i];
        rec.y = __int_as_float((int)(cell * 8192u) + gb);
        xpk[pos] = rec;

        // overall (log softmax) term
        const unsigned ix2  = (unsigned)cxg_tot[i];
        const unsigned cell2 = ix2 / N_GTOT;
        const unsigned g2    = ix2 - cell2 * N_GTOT;
        float logit = ob[g2];
#pragma unroll
        for (int l = 0; l < N_LAT; ++l)
            logit = fmaf(latent[cell2 * N_LAT + l], osw[g2 * N_LAT + l], logit);
        ovs += (double)(logit - lse[cell2] + LOG_NGT);
    }
#pragma unroll
    for (int off = 32; off; off >>= 1) ovs += __shfl_xor(ovs, off);
    __shared__ double part[4];
    if ((t & 63) == 0) part[t >> 6] = ovs;
    __syncthreads();
    if (t == 0)
        atomicAdd(out, (float)(-(part[0] + part[1] + part[2] + part[3])));
}

// ---------------------------------------------------------------------------
// Spline kernel: one wave per cut (knots on lanes), SPLIT*4 waves per gene
// bucket. Gene's 10x129 slope row lives in VGPRs (w0: k=lane, w1: k=64+lane,
// w2: k=128 replicated). Software-pipelined: packed record prefetched 2
// iterations ahead, latent/sbase rows 1 iteration ahead.
// ---------------------------------------------------------------------------
__global__ __launch_bounds__(256, 4) void spline_kernel(
    const float* __restrict__ latent,   // [N_CELLS, N_LAT]
    const int*   __restrict__ genes_oi, // [N_GOI]
    const float* __restrict__ hsw,      // [N_GTOT, N_LAT, N_KNOTS]
    const float* __restrict__ sbase,    // [N_GTOT, N_KNOTS]
    const int*   __restrict__ offs,     // [N_GOI+1]
    const float2* __restrict__ xpk,     // packed {coord, cell*8192+gb}
    float* __restrict__ out)
{
    const int goi  = blockIdx.x / SPLIT;
    const int sub  = blockIdx.x % SPLIT;
    const int lane = threadIdx.x & 63;
    const int wav  = threadIdx.x >> 6;
    const int g    = genes_oi[goi];

    // Gene's slope row into registers.
    float w0[N_LAT], w1[N_LAT], w2[N_LAT];
#pragma unroll
    for (int l = 0; l < N_LAT; ++l) {
        const float* p = hsw + (g * N_LAT + l) * N_KNOTS;
        w0[l] = p[lane];
        w1[l] = p[64 + lane];
        w2[l] = p[128];
    }

    const int begin = offs[goi];
    const int end   = offs[goi + 1];
    const int S     = SPLIT * 4;
    double acc = 0.0;

    int c0 = begin + sub * 4 + wav;
    if (c0 < end) {
        const int last = end - 1;
        // pipeline state: cur packed (for cut c), next packed, cur rows
        float2 pcur = xpk[c0];
        int cn1 = min(c0 + S, last);
        float2 pnext = xpk[cn1];

        int pk    = __float_as_int(pcur.y);
        int cell  = pk >> 13;
        int gb    = pk & 8191;
        float lat[N_LAT];
#pragma unroll
        for (int l = 0; l < N_LAT; ++l) lat[l] = latent[cell * N_LAT + l];
        const float* bp = sbase + gb * N_KNOTS;
        float sb0 = bp[lane], sb1 = bp[64 + lane], sb2 = bp[128];

        for (int c = c0; c < end; c += S) {
            // prefetch packed for c+2S
            int c2 = min(c + 2 * S, last);
            float2 p2 = xpk[c2];
            // issue row loads for next cut (pnext already resident)
            int pkn   = __float_as_int(pnext.y);
            int celln = pkn >> 13;
            int gbn   = pkn & 8191;
            float latN[N_LAT];
#pragma unroll
            for (int l = 0; l < N_LAT; ++l) latN[l] = latent[celln * N_LAT + l];
            const float* bpn = sbase + gbn * N_KNOTS;
            float sb0n = bpn[lane], sb1n = bpn[64 + lane], sb2n = bpn[128];

            // ---- compute current cut ----
            float h0 = sb0, h1 = sb1, h2 = sb2;
#pragma unroll
            for (int l = 0; l < N_LAT; ++l) {
                h0 = fmaf(lat[l], w0[l], h0);
                h1 = fmaf(lat[l], w1[l], h1);
                h2 = fmaf(lat[l], w2[l], h2);
            }
            // pdf invariant to constant shift of heights -> skip max-subtract
            float u0 = __expf(h0), u1 = __expf(h1), u2 = __expf(h2);
            float ufirst = __shfl(u0, 0);
            float s = u0 + u1;                       // covers k=0..127
#pragma unroll
            for (int off = 32; off; off >>= 1) s += __shfl_xor(s, off);
            s += u2;                                 // k=0..128
            float norm = (s - 0.5f * (ufirst + u2)) * (1.0f / (float)NBINS);

            float xsv = fminf(fmaxf(pcur.x, 0.0f), 1.0f - 1e-6f) * (float)NBINS;
            int   b   = (int)xsv;
            b = b < NBINS - 1 ? b : NBINS - 1;
            float alpha = xsv - (float)b;
            int   kk = b + 1;
            float left  = (b < 64) ? __shfl(u0, b) : __shfl(u1, b - 64);
            float right = (kk < 64) ? __shfl(u0, kk)
                                    : (kk < 128 ? __shfl(u1, kk - 64) : u2);
            float lh = __logf(fmaf(alpha, right - left, left)) - __logf(norm);
            acc += (double)lh;

            // ---- rotate pipeline ----
            pcur = pnext; pnext = p2;
#pragma unroll
            for (int l = 0; l < N_LAT; ++l) lat[l] = latN[l];
            sb0 = sb0n; sb1 = sb1n; sb2 = sb2n;
        }
    }

    __shared__ double part[4];
    if (threadIdx.x < 4) part[threadIdx.x] = 0.0;
    __syncthreads();
    if (lane == 0) part[wav] = acc;
    __syncthreads();
    if (threadIdx.x == 0) {
        double tot = part[0] + part[1] + part[2] + part[3];
        atomicAdd(out, (float)(-tot));
    }
}

// ---------------------------------------------------------------------------
extern "C" void kernel_launch(void* const* d_in, const int* in_sizes, int n_in,
                              void* d_out, int out_size, void* d_ws, size_t ws_size,
                              hipStream_t stream)
{
    const float* latent   = (const float*)d_in[0];
    const float* coords   = (const float*)d_in[1];
    const int*   genes_oi = (const int*)  d_in[2];
    const int*   cxg      = (const int*)  d_in[3];
    const int*   cxg_tot  = (const int*)  d_in[4];
    const int*   glocal   = (const int*)  d_in[5];
    const float* hsw      = (const float*)d_in[6];
    const float* osw      = (const float*)d_in[7];
    const float* ob       = (const float*)d_in[8];
    const float* sbase    = (const float*)d_in[9];
    const int ncuts = in_sizes[1];

    char* ws = (char*)d_ws;
    float*  lse    = (float*)ws;                // 1000 floats
    int*    counts = (int*)(ws + 4096);         // 500 ints
    int*    offs   = (int*)(ws + 8192);         // 501 ints
    int*    cursor = (int*)(ws + 12288);        // 500 ints
    float2* xpk    = (float2*)(ws + 16384);     // ncuts float2 (8 MB)
    float*  out    = (float*)d_out;

    hipMemsetAsync(out, 0, sizeof(float), stream);
    hipMemsetAsync(counts, 0, N_GOI * sizeof(int), stream);

    lse_kernel<<<N_CELLS, 256, 0, stream>>>(latent, osw, ob, lse);
    hist_kernel<<<256, 256, 0, stream>>>(cxg, counts, ncuts);
    scan_kernel<<<1, 512, 0, stream>>>(counts, offs, cursor);
    gather_kernel<<<512, 256, 0, stream>>>(
        latent, coords, genes_oi, cxg, cxg_tot, glocal,
        osw, ob, lse, cursor, xpk, out, ncuts);
    spline_kernel<<<N_GOI * SPLIT, 256, 0, stream>>>(
        latent, genes_oi, hsw, sbase, offs, xpk, out);
}

// Round 3
// 369.328 us; speedup vs baseline: 3.2717x; 1.6721x over previous
//
#include <hip/hip_runtime.h>
#include <hip/hip_bf16.h>

// Problem constants (match reference)
#define N_CELLS   1000
#define N_GOI     500
#define N_GTOT    5000
#define N_LAT     10
#define NBINS     128     // K
#define N_KNOTS   129     // K+1
#define LOG_NGT   8.517193191416238f   // log(5000)
#define SPLIT     8       // blocks per gene bucket (spline kernel)
#define NREP      64      // cursor replicas per gene bin
#define NSEG      (N_GOI * NREP)       // 32000 segment counters
#define NSEG_PAD  32768                // padded to 32*1024 for the scan

// rep is a pure function of cut index -> hist and scatter agree.
#define REP_OF(i) (((unsigned)(i) >> 10) & (NREP - 1))

// ---------------------------------------------------------------------------
// Kernel 1: per-cell logsumexp over all 5000 genes of (baseline + latent@W^T)
// One block per cell.
// ---------------------------------------------------------------------------
__global__ __launch_bounds__(256) void lse_kernel(
    const float* __restrict__ latent,   // [N_CELLS, N_LAT]
    const float* __restrict__ osw,      // [N_GTOT, N_LAT]
    const float* __restrict__ ob,       // [N_GTOT]
    float* __restrict__ lse)            // [N_CELLS]
{
    const int c = blockIdx.x;
    const int t = threadIdx.x;
    float lat[N_LAT];
#pragma unroll
    for (int l = 0; l < N_LAT; ++l) lat[l] = latent[c * N_LAT + l];

    __shared__ float xsh[N_GTOT];
    float m = -1e30f;
    for (int g = t; g < N_GTOT; g += 256) {
        float v = ob[g];
#pragma unroll
        for (int l = 0; l < N_LAT; ++l) v = fmaf(lat[l], osw[g * N_LAT + l], v);
        xsh[g] = v;
        m = fmaxf(m, v);
    }
#pragma unroll
    for (int off = 32; off; off >>= 1) m = fmaxf(m, __shfl_xor(m, off));
    __shared__ float wm[4];
    if ((t & 63) == 0) wm[t >> 6] = m;
    __syncthreads();
    m = fmaxf(fmaxf(wm[0], wm[1]), fmaxf(wm[2], wm[3]));

    float s = 0.0f;
    for (int g = t; g < N_GTOT; g += 256) s += __expf(xsh[g] - m);
#pragma unroll
    for (int off = 32; off; off >>= 1) s += __shfl_xor(s, off);
    __shared__ float wsum[4];
    if ((t & 63) == 0) wsum[t >> 6] = s;
    __syncthreads();
    if (t == 0) lse[c] = m + __logf(wsum[0] + wsum[1] + wsum[2] + wsum[3]);
}

// ---------------------------------------------------------------------------
// K1: histogram into (bin, rep) counters. One block per 1024-cut chunk so
// the chunk's rep is block-uniform; LDS-privatized; flush atomics see only
// ~(nchunks/64)-way contention and need no return value.
// ---------------------------------------------------------------------------
__global__ __launch_bounds__(256) void hist_kernel(
    const int* __restrict__ cxg, int* __restrict__ counts, int n)
{
    __shared__ int h[N_GOI];
    const int t = threadIdx.x;
    for (int b = t; b < N_GOI; b += 256) h[b] = 0;
    __syncthreads();
    const int base = blockIdx.x << 10;
    const int rep  = blockIdx.x & (NREP - 1);
#pragma unroll
    for (int j = 0; j < 4; ++j) {
        int i = base + t + j * 256;
        if (i < n) atomicAdd(&h[((unsigned)cxg[i]) % N_GOI], 1);
    }
    __syncthreads();
    for (int b = t; b < N_GOI; b += 256) {
        int v = h[b];
        if (v) atomicAdd(&counts[b * NREP + rep], v);
    }
}

// ---------------------------------------------------------------------------
// K2: single-block exclusive scan over the 32768 (padded) counters in
// bin-major order -> per-bin segments are contiguous. Writes the running
// base into cursor[] and per-bin starts into offs[].
// ---------------------------------------------------------------------------
__global__ __launch_bounds__(1024) void scan_kernel(
    const int* __restrict__ counts, int* __restrict__ cursor,
    int* __restrict__ offs)
{
    const int t = threadIdx.x;
    const int base = t * 32;
    int local = 0;
#pragma unroll
    for (int j = 0; j < 32; ++j) local += counts[base + j];

    __shared__ int ssum[1024];
    ssum[t] = local;
    __syncthreads();
    for (int d = 1; d < 1024; d <<= 1) {
        int a = (t >= d) ? ssum[t - d] : 0;
        __syncthreads();
        ssum[t] += a;
        __syncthreads();
    }
    int run = ssum[t] - local;   // exclusive prefix of this thread's chunk

#pragma unroll
    for (int j = 0; j < 32; ++j) {
        int idx = base + j;
        int v = counts[idx];
        cursor[idx] = run;
        if ((idx & (NREP - 1)) == 0 && idx < NSEG) offs[idx >> 6] = run;
        run += v;
    }
    if (t == 1023) offs[N_GOI] = run;   // == total n (padded tail counts 0)
}

// ---------------------------------------------------------------------------
// K3 fused gather: thread-per-cut (grid-stride).
//  - computes the full overall/log-softmax term and reduces it into out
//  - packs {coord, cell*8192+gb} into the cut's (bin,rep) segment; the
//    cursor atomic sees only ~n/32000 increments -> no serialization.
// ---------------------------------------------------------------------------
__global__ __launch_bounds__(256) void gather_kernel(
    const float* __restrict__ latent,   // [N_CELLS, N_LAT]
    const float* __restrict__ coords,   // [ncuts]
    const int*   __restrict__ genes_oi, // [N_GOI]
    const int*   __restrict__ cxg,      // cut_local_cellxgene_ix  [ncuts]
    const int*   __restrict__ cxg_tot,  // cut_localcellxgene_ix   [ncuts]
    const int*   __restrict__ glocal,   // cut_local_gene_ix       [ncuts]
    const float* __restrict__ osw,      // [N_GTOT, N_LAT]
    const float* __restrict__ ob,       // [N_GTOT]
    const float* __restrict__ lse,      // [N_CELLS]
    int*   __restrict__ cursor,         // [NSEG]
    float2* __restrict__ xpk,           // [ncuts] packed records
    float* __restrict__ out, int n)
{
    const int t = threadIdx.x;
    const int stride = gridDim.x * 256;
    double ovs = 0.0;
    for (int i = blockIdx.x * 256 + t; i < n; i += stride) {
        const unsigned ix   = (unsigned)cxg[i];
        const unsigned bin  = ix % N_GOI;
        const unsigned cell = ix / N_GOI;
        const int gb = genes_oi[glocal[i]];
        const int pos = atomicAdd(&cursor[bin * NREP + REP_OF(i)], 1);
        float2 rec;
        rec.x = coords[i];
        rec.y = __int_as_float((int)(cell * 8192u) + gb);
        xpk[pos] = rec;

        // overall (log softmax) term
        const unsigned ix2   = (unsigned)cxg_tot[i];
        const unsigned cell2 = ix2 / N_GTOT;
        const unsigned g2    = ix2 - cell2 * N_GTOT;
        float logit = ob[g2];
#pragma unroll
        for (int l = 0; l < N_LAT; ++l)
            logit = fmaf(latent[cell2 * N_LAT + l], osw[g2 * N_LAT + l], logit);
        ovs += (double)(logit - lse[cell2] + LOG_NGT);
    }
#pragma unroll
    for (int off = 32; off; off >>= 1) ovs += __shfl_xor(ovs, off);
    __shared__ double part[4];
    if ((t & 63) == 0) part[t >> 6] = ovs;
    __syncthreads();
    if (t == 0)
        atomicAdd(out, (float)(-(part[0] + part[1] + part[2] + part[3])));
}

// ---------------------------------------------------------------------------
// Spline kernel: one wave per cut (knots on lanes), SPLIT*4 waves per gene
// bucket. Gene's 10x129 slope row lives in VGPRs (w0: k=lane, w1: k=64+lane,
// w2: k=128 replicated). Software-pipelined: packed record prefetched 2
// iterations ahead, latent/sbase rows 1 iteration ahead.
// ---------------------------------------------------------------------------
__global__ __launch_bounds__(256, 4) void spline_kernel(
    const float* __restrict__ latent,   // [N_CELLS, N_LAT]
    const int*   __restrict__ genes_oi, // [N_GOI]
    const float* __restrict__ hsw,      // [N_GTOT, N_LAT, N_KNOTS]
    const float* __restrict__ sbase,    // [N_GTOT, N_KNOTS]
    const int*   __restrict__ offs,     // [N_GOI+1]
    const float2* __restrict__ xpk,     // packed {coord, cell*8192+gb}
    float* __restrict__ out)
{
    const int goi  = blockIdx.x / SPLIT;
    const int sub  = blockIdx.x % SPLIT;
    const int lane = threadIdx.x & 63;
    const int wav  = threadIdx.x >> 6;
    const int g    = genes_oi[goi];

    // Gene's slope row into registers.
    float w0[N_LAT], w1[N_LAT], w2[N_LAT];
#pragma unroll
    for (int l = 0; l < N_LAT; ++l) {
        const float* p = hsw + (g * N_LAT + l) * N_KNOTS;
        w0[l] = p[lane];
        w1[l] = p[64 + lane];
        w2[l] = p[128];
    }

    const int begin = offs[goi];
    const int end   = offs[goi + 1];
    const int S     = SPLIT * 4;
    double acc = 0.0;

    int c0 = begin + sub * 4 + wav;
    if (c0 < end) {
        const int last = end - 1;
        // pipeline state: cur packed (for cut c), next packed, cur rows
        float2 pcur = xpk[c0];
        int cn1 = min(c0 + S, last);
        float2 pnext = xpk[cn1];

        int pk    = __float_as_int(pcur.y);
        int cell  = pk >> 13;
        int gb    = pk & 8191;
        float lat[N_LAT];
#pragma unroll
        for (int l = 0; l < N_LAT; ++l) lat[l] = latent[cell * N_LAT + l];
        const float* bp = sbase + gb * N_KNOTS;
        float sb0 = bp[lane], sb1 = bp[64 + lane], sb2 = bp[128];

        for (int c = c0; c < end; c += S) {
            // prefetch packed for c+2S
            int c2 = min(c + 2 * S, last);
            float2 p2 = xpk[c2];
            // issue row loads for next cut (pnext already resident)
            int pkn   = __float_as_int(pnext.y);
            int celln = pkn >> 13;
            int gbn   = pkn & 8191;
            float latN[N_LAT];
#pragma unroll
            for (int l = 0; l < N_LAT; ++l) latN[l] = latent[celln * N_LAT + l];
            const float* bpn = sbase + gbn * N_KNOTS;
            float sb0n = bpn[lane], sb1n = bpn[64 + lane], sb2n = bpn[128];

            // ---- compute current cut ----
            float h0 = sb0, h1 = sb1, h2 = sb2;
#pragma unroll
            for (int l = 0; l < N_LAT; ++l) {
                h0 = fmaf(lat[l], w0[l], h0);
                h1 = fmaf(lat[l], w1[l], h1);
                h2 = fmaf(lat[l], w2[l], h2);
            }
            // pdf invariant to constant shift of heights -> skip max-subtract
            float u0 = __expf(h0), u1 = __expf(h1), u2 = __expf(h2);
            float ufirst = __shfl(u0, 0);
            float s = u0 + u1;                       // covers k=0..127
#pragma unroll
            for (int off = 32; off; off >>= 1) s += __shfl_xor(s, off);
            s += u2;                                 // k=0..128
            float norm = (s - 0.5f * (ufirst + u2)) * (1.0f / (float)NBINS);

            float xsv = fminf(fmaxf(pcur.x, 0.0f), 1.0f - 1e-6f) * (float)NBINS;
            int   b   = (int)xsv;
            b = b < NBINS - 1 ? b : NBINS - 1;
            float alpha = xsv - (float)b;
            int   kk = b + 1;
            float left  = (b < 64) ? __shfl(u0, b) : __shfl(u1, b - 64);
            float right = (kk < 64) ? __shfl(u0, kk)
                                    : (kk < 128 ? __shfl(u1, kk - 64) : u2);
            float lh = __logf(fmaf(alpha, right - left, left)) - __logf(norm);
            acc += (double)lh;

            // ---- rotate pipeline ----
            pcur = pnext; pnext = p2;
#pragma unroll
            for (int l = 0; l < N_LAT; ++l) lat[l] = latN[l];
            sb0 = sb0n; sb1 = sb1n; sb2 = sb2n;
        }
    }

    __shared__ double part[4];
    if (threadIdx.x < 4) part[threadIdx.x] = 0.0;
    __syncthreads();
    if (lane == 0) part[wav] = acc;
    __syncthreads();
    if (threadIdx.x == 0) {
        double tot = part[0] + part[1] + part[2] + part[3];
        atomicAdd(out, (float)(-tot));
    }
}

// ---------------------------------------------------------------------------
extern "C" void kernel_launch(void* const* d_in, const int* in_sizes, int n_in,
                              void* d_out, int out_size, void* d_ws, size_t ws_size,
                              hipStream_t stream)
{
    const float* latent   = (const float*)d_in[0];
    const float* coords   = (const float*)d_in[1];
    const int*   genes_oi = (const int*)  d_in[2];
    const int*   cxg      = (const int*)  d_in[3];
    const int*   cxg_tot  = (const int*)  d_in[4];
    const int*   glocal   = (const int*)  d_in[5];
    const float* hsw      = (const float*)d_in[6];
    const float* osw      = (const float*)d_in[7];
    const float* ob       = (const float*)d_in[8];
    const float* sbase    = (const float*)d_in[9];
    const int ncuts = in_sizes[1];

    char* ws = (char*)d_ws;
    float*  lse    = (float*)ws;                     // 1000 floats
    int*    offs   = (int*)(ws + 4096);              // 501 ints
    int*    counts = (int*)(ws + 8192);              // 32768 ints (128 KB)
    int*    cursor = (int*)(ws + 8192 + 131072);     // 32768 ints (128 KB)
    float2* xpk    = (float2*)(ws + 8192 + 262144);  // ncuts float2 (8 MB)
    float*  out    = (float*)d_out;

    hipMemsetAsync(out, 0, sizeof(float), stream);
    hipMemsetAsync(counts, 0, NSEG_PAD * sizeof(int), stream);

    const int nchunks = (ncuts + 1023) >> 10;
    lse_kernel<<<N_CELLS, 256, 0, stream>>>(latent, osw, ob, lse);
    hist_kernel<<<nchunks, 256, 0, stream>>>(cxg, counts, ncuts);
    scan_kernel<<<1, 1024, 0, stream>>>(counts, cursor, offs);
    gather_kernel<<<2048, 256, 0, stream>>>(
        latent, coords, genes_oi, cxg, cxg_tot, glocal,
        osw, ob, lse, cursor, xpk, out, ncuts);
    spline_kernel<<<N_GOI * SPLIT, 256, 0, stream>>>(
        latent, genes_oi, hsw, sbase, offs, xpk, out);
}